// Round 1
// baseline (106.328 us; speedup 1.0000x reference)
//
#include <hip/hip_runtime.h>
#include <hip/hip_bf16.h>
#include <math.h>

typedef unsigned int u32;
typedef unsigned short u16;
typedef __bf16 bf16_t;
typedef bf16_t bf16x8 __attribute__((ext_vector_type(8)));
typedef float f32x4 __attribute__((ext_vector_type(4)));

#define B_N 8192
#define D_K 256
#define NCLS 360
#define BM 128
#define BN 64
#define NSPLIT 8
#define NT ((B_N / NSPLIT) / BN)   // 16
#define WROWS 32

// -log2(e)/T  and ln(2)
#define SCALE2 (-20.609929155556627f)   // -(1/0.07)*log2(e)
#define LN2 (0.6931471805599453f)
#define INV_T (14.285714285714286f)     // 1/0.07

__device__ __forceinline__ float fexp2(float x) { return __builtin_amdgcn_exp2f(x); }

__device__ __forceinline__ u16 f2bf(float x) {
  u32 u = __float_as_uint(x);
  u32 r = (u + 0x7fffu + ((u >> 16) & 1u)) >> 16;
  return (u16)r;
}

__device__ __forceinline__ void gl_lds16(const void* g, void* l) {
  __builtin_amdgcn_global_load_lds(
      (const __attribute__((address_space(1))) u32*)g,
      (__attribute__((address_space(3))) u32*)l, 16, 0, 0);
}

// ---------------- K1: convert f32->bf16, class sums (fp32 atomics), histogram
__global__ void k_prep(const float* __restrict__ f, const int* __restrict__ lab,
                       u16* __restrict__ fbf, float* __restrict__ csum,
                       int* __restrict__ hist) {
  int t = blockIdx.x * 256 + threadIdx.x;
  int e4 = t * 4;
  int row = e4 >> 8;
  int col = e4 & 255;
  const float4 v = *reinterpret_cast<const float4*>(f + e4);
  ushort4 b;
  b.x = f2bf(v.x); b.y = f2bf(v.y); b.z = f2bf(v.z); b.w = f2bf(v.w);
  *reinterpret_cast<ushort4*>(fbf + e4) = b;
  int lb = lab[row];
  float* cs = csum + lb * 256 + col;
  atomicAdd(cs + 0, v.x);
  atomicAdd(cs + 1, v.y);
  atomicAdd(cs + 2, v.z);
  atomicAdd(cs + 3, v.w);
  if (col == 0) atomicAdd(hist + lb, 1);
}

// ---------------- K2: fused pairwise-dot + online reductions
// grid = 64 row-blocks * NSPLIT col-splits; block = 256 thr (4 waves x 32 rows)
__device__ __forceinline__ void stage_tile(const u16* __restrict__ fb, int col0,
                                           u16* buf, int w, int lane) {
#pragma unroll
  for (int it = 0; it < 8; ++it) {
    int lin = (w * 8 + it) * 1024 + lane * 16;  // byte offset in tile
    int row = lin >> 9;                          // /512B per row
    int c = (lin >> 4) & 31;                     // 16B chunk in row
    int q = c ^ (row & 7);                       // pre-swizzled source chunk
    const u16* src = fb + (size_t)(col0 + row) * D_K + q * 8;
    u16* dst = buf + (w * 8 + it) * 512;         // wave-uniform base (u16 elems)
    gl_lds16(src, dst);
  }
}

__global__ __launch_bounds__(256, 2) void k_main(const u16* __restrict__ fb,
                                                 const int* __restrict__ lab,
                                                 float4* __restrict__ part) {
  __shared__ __align__(16) u16 Bs[2][BN * D_K];  // 2 x 32KB

  const int tid = threadIdx.x;
  const int lane = tid & 63;
  const int w = tid >> 6;
  const int t15 = lane & 15;
  const int g = lane >> 4;
  const int t7 = t15 & 7;
  const int rb = blockIdx.x & 63;
  const int sp = blockIdx.x >> 6;
  const int rowbase = rb * BM + w * WROWS;
  const int colbase = sp * (B_N / NSPLIT);

  // A fragments: 32 rows x 256 K, register resident (16 x 16B)
  bf16x8 A[2][8];
#pragma unroll
  for (int rs = 0; rs < 2; ++rs)
#pragma unroll
    for (int kk = 0; kk < 8; ++kk) {
      const u16* p = fb + (size_t)(rowbase + rs * 16 + t15) * D_K + kk * 32 + g * 8;
      A[rs][kk] = *reinterpret_cast<const bf16x8*>(p);
    }

  int labr[8];
#pragma unroll
  for (int rs = 0; rs < 2; ++rs)
#pragma unroll
    for (int q = 0; q < 4; ++q)
      labr[rs * 4 + q] = lab[rowbase + rs * 16 + g * 4 + q];

  float m2[8], Ea[8], Ep[8];
#pragma unroll
  for (int i = 0; i < 8; ++i) { m2[i] = -1e30f; Ea[i] = 0.f; Ep[i] = 0.f; }

  stage_tile(fb, colbase, &Bs[0][0], w, lane);
  __syncthreads();

  for (int t = 0; t < NT; ++t) {
    if (t + 1 < NT) stage_tile(fb, colbase + (t + 1) * BN, &Bs[(t + 1) & 1][0], w, lane);

    const u16* bufp = &Bs[t & 1][0];
    f32x4 C[2][4];
    const f32x4 z4 = {0.f, 0.f, 0.f, 0.f};
#pragma unroll
    for (int rs = 0; rs < 2; ++rs)
#pragma unroll
      for (int s = 0; s < 4; ++s) C[rs][s] = z4;

#pragma unroll
    for (int kk = 0; kk < 8; ++kk) {
      bf16x8 Bf[4];
#pragma unroll
      for (int s = 0; s < 4; ++s) {
        int rowB = s * 16 + t15;
        int q = (kk * 4 + g) ^ t7;
        Bf[s] = *reinterpret_cast<const bf16x8*>(bufp + rowB * D_K + q * 8);
      }
#pragma unroll
      for (int rs = 0; rs < 2; ++rs)
#pragma unroll
        for (int s = 0; s < 4; ++s)
          C[rs][s] = __builtin_amdgcn_mfma_f32_16x16x32_bf16(A[rs][kk], Bf[s], C[rs][s], 0, 0, 0);
    }

    // epilogue: online max / exp sums
    int cl[4];
#pragma unroll
    for (int s = 0; s < 4; ++s) cl[s] = lab[colbase + t * 64 + s * 16 + t15];
#pragma unroll
    for (int rs = 0; rs < 2; ++rs) {
#pragma unroll
      for (int q = 0; q < 4; ++q) {
        const int slot = rs * 4 + q;
        float v0 = C[rs][0][q] * SCALE2;
        float v1 = C[rs][1][q] * SCALE2;
        float v2 = C[rs][2][q] * SCALE2;
        float v3 = C[rs][3][q] * SCALE2;
        float tm = fmaxf(fmaxf(v0, v1), fmaxf(v2, v3));
        float nm = fmaxf(m2[slot], tm);
        float sc = fexp2(m2[slot] - nm);
        float e0 = fexp2(v0 - nm), e1 = fexp2(v1 - nm);
        float e2 = fexp2(v2 - nm), e3 = fexp2(v3 - nm);
        Ea[slot] = Ea[slot] * sc + ((e0 + e1) + (e2 + e3));
        const int lr = labr[slot];
        float p0 = (cl[0] == lr) ? e0 : 0.f;
        float p1 = (cl[1] == lr) ? e1 : 0.f;
        float p2 = (cl[2] == lr) ? e2 : 0.f;
        float p3 = (cl[3] == lr) ? e3 : 0.f;
        Ep[slot] = Ep[slot] * sc + ((p0 + p1) + (p2 + p3));
        m2[slot] = nm;
      }
    }
    __syncthreads();
  }

  // cross-lane merge: 16 lanes of a group hold disjoint column subsets of same rows
#pragma unroll
  for (int st = 1; st < 16; st <<= 1) {
#pragma unroll
    for (int i = 0; i < 8; ++i) {
      float om = __shfl_xor(m2[i], st);
      float oa = __shfl_xor(Ea[i], st);
      float op = __shfl_xor(Ep[i], st);
      float nm = fmaxf(m2[i], om);
      float sa = fexp2(m2[i] - nm), sb = fexp2(om - nm);
      Ea[i] = Ea[i] * sa + oa * sb;
      Ep[i] = Ep[i] * sa + op * sb;
      m2[i] = nm;
    }
  }
  if (t15 == 0) {
#pragma unroll
    for (int rs = 0; rs < 2; ++rs)
#pragma unroll
      for (int q = 0; q < 4; ++q) {
        int row = rowbase + rs * 16 + g * 4 + q;
        part[sp * B_N + row] = make_float4(m2[rs * 4 + q], Ea[rs * 4 + q], Ep[rs * 4 + q], 0.f);
      }
  }
}

// ---------------- K3: per-row finalize (merge splits, exact fp32 positive sum)
__global__ void k_final(const float* __restrict__ f, const int* __restrict__ lab,
                        const float* __restrict__ csum, const int* __restrict__ hist,
                        const float4* __restrict__ part, float* __restrict__ loss) {
  int w = threadIdx.x >> 6, lane = threadIdx.x & 63;
  int row = blockIdx.x * 4 + w;
  int lb = lab[row];
  const float4 a = reinterpret_cast<const float4*>(f + row * 256)[lane];
  const float4 c = reinterpret_cast<const float4*>(csum + lb * 256)[lane];
  float sd = a.x * c.x + a.y * c.y + a.z * c.z + a.w * c.w;
  float nn = a.x * a.x + a.y * a.y + a.z * a.z + a.w * a.w;
#pragma unroll
  for (int off = 32; off > 0; off >>= 1) {
    sd += __shfl_down(sd, off);
    nn += __shfl_down(nn, off);
  }
  if (lane == 0) {
    float m2 = -1e30f, Ea = 0.f, Ep = 0.f;
#pragma unroll
    for (int s = 0; s < NSPLIT; ++s) {
      float4 p = part[s * B_N + row];
      float nm = fmaxf(m2, p.x);
      float sa = fexp2(m2 - nm), sb = fexp2(p.x - nm);
      Ea = Ea * sa + p.y * sb;
      Ep = Ep * sa + p.z * sb;
      m2 = nm;
    }
    float v2s = nn * SCALE2;               // self logit in log2 units
    float eself = fexp2(v2s - m2);
    float Epa = fmaxf(Ep - eself, 0.f);    // positives excluding self
    float En = fmaxf(Ea - Ep, 0.f);        // negatives (label differs)
    int cntp = hist[lb] - 1;
    float cntn = (float)(B_N - 1 - cntp);
    float denom = Epa + En / (cntn + 1e-8f);
    float Sadc = (sd - nn) * (-INV_T);     // exact fp32 sum of positive logits
    float num = Sadc - (float)cntp * (m2 * LN2) - (float)cntp * logf(denom);
    float dv = (cntp == 0) ? 1.f : (float)cntp;
    loss[row] = num / dv;
  }
}

// ---------------- K4: mean over rows
__global__ void k_reduce(const float* __restrict__ loss, float* __restrict__ out) {
  __shared__ float sm[256];
  int tid = threadIdx.x;
  float a = 0.f;
  for (int i = tid; i < B_N; i += 256) a += loss[i];
  sm[tid] = a;
  __syncthreads();
#pragma unroll
  for (int s = 128; s > 0; s >>= 1) {
    if (tid < s) sm[tid] += sm[tid + s];
    __syncthreads();
  }
  if (tid == 0) out[0] = sm[0] * (1.f / (float)B_N);
}

extern "C" void kernel_launch(void* const* d_in, const int* in_sizes, int n_in,
                              void* d_out, int out_size, void* d_ws, size_t ws_size,
                              hipStream_t stream) {
  const float* f = (const float*)d_in[0];
  const int* lab = (const int*)d_in[1];
  // d_in[2] (sigma) unused by the reference forward value

  char* ws = (char*)d_ws;
  float* csum = (float*)ws;                                  // 360*256*4 = 368640
  int* hist = (int*)(ws + 368640);                           // 1440
  u16* fbf = (u16*)(ws + 524288);                            // 4 MB
  float4* part = (float4*)(ws + 524288 + 4194304);           // 8*8192*16 = 1 MB
  float* loss = (float*)(ws + 524288 + 4194304 + 1048576);   // 32 KB

  hipMemsetAsync(ws, 0, 370080, stream);
  k_prep<<<2048, 256, 0, stream>>>(f, lab, fbf, csum, hist);
  k_main<<<64 * NSPLIT, 256, 0, stream>>>(fbf, lab, part);
  k_final<<<B_N / 4, 256, 0, stream>>>(f, lab, csum, hist, part, loss);
  k_reduce<<<1, 256, 0, stream>>>(loss, (float*)d_out);
}